// Round 2
// baseline (493.535 us; speedup 1.0000x reference)
//
#include <hip/hip_runtime.h>
#include <stdint.h>

typedef __attribute__((ext_vector_type(8))) short short8;      // 8 x bf16 (4 VGPRs) MFMA A/B frag
typedef __attribute__((ext_vector_type(4))) float f32x4;       // MFMA C/D frag
typedef __attribute__((ext_vector_type(4))) unsigned short u16x4;

typedef unsigned short ushort_t;

__device__ __forceinline__ unsigned short f2bf(float f) {
    union { float f; uint32_t u; } c; c.f = f;
    uint32_t u = c.u;
    return (unsigned short)((u + 0x7FFFu + ((u >> 16) & 1u)) >> 16);   // RNE
}

__device__ __forceinline__ f32x4 mfma16(short8 a, short8 b, f32x4 c) {
    return __builtin_amdgcn_mfma_f32_16x16x32_bf16(a, b, c, 0, 0, 0);
}

#define LOG2E 1.4426950408889634f

// ---------------- converters ----------------

__global__ __launch_bounds__(256) void cvt_x_k(const float4* __restrict__ in,
                                               u16x4* __restrict__ out, int n4) {
    int i = blockIdx.x * 256 + threadIdx.x;
    if (i < n4) {
        float4 v = in[i];
        u16x4 o;
        o[0] = f2bf(v.x); o[1] = f2bf(v.y); o[2] = f2bf(v.z); o[3] = f2bf(v.w);
        out[i] = o;
    }
}

// kv_w (131072 groups) + proj_w (65536) + q_global*scale*log2e (100352) = 296960 groups
__global__ __launch_bounds__(256) void cvt_small_k(const float4* __restrict__ kvw,
                                                   const float4* __restrict__ pw,
                                                   const float4* __restrict__ qg,
                                                   u16x4* __restrict__ kvwb,
                                                   u16x4* __restrict__ pwb,
                                                   u16x4* __restrict__ qb) {
    // 32^-0.5 * log2(e): softmax computed in exp2 domain
    const float qs = 0.17677669529663687f * LOG2E;
    int i = blockIdx.x * 256 + threadIdx.x;
    if (i < 131072) {
        float4 v = kvw[i];
        u16x4 o; o[0]=f2bf(v.x); o[1]=f2bf(v.y); o[2]=f2bf(v.z); o[3]=f2bf(v.w);
        kvwb[i] = o;
    } else if (i < 196608) {
        int j = i - 131072;
        float4 v = pw[j];
        u16x4 o; o[0]=f2bf(v.x); o[1]=f2bf(v.y); o[2]=f2bf(v.z); o[3]=f2bf(v.w);
        pwb[j] = o;
    } else {
        int j = i - 196608;   // < 100352
        float4 v = qg[j];
        u16x4 o; o[0]=f2bf(v.x*qs); o[1]=f2bf(v.y*qs); o[2]=f2bf(v.z*qs); o[3]=f2bf(v.w*qs);
        qb[j] = o;
    }
}

// bias_full[h][i][j], i,j in [0,208); -1e30 on pad so softmax masks pad keys.
// Values pre-scaled by log2(e) (softmax runs in exp2 domain).
__global__ __launch_bounds__(256) void bias_k(const float* __restrict__ bt,
                                              float* __restrict__ out) {
    int idx = blockIdx.x * 256 + threadIdx.x;        // 16*208*208 = 692224 exact
    int h = idx / 43264;
    int rem = idx - h * 43264;
    int i = rem / 208;
    int j = rem - i * 208;
    float v = -1e30f;
    if (i < 196 && j < 196) {
        int t1 = i / 49, r1 = i - t1 * 49, h1 = r1 / 7, w1 = r1 - h1 * 7;
        int t2 = j / 49, r2 = j - t2 * 49, h2 = r2 / 7, w2 = r2 - h2 * 7;
        int bi = (t1 - t2 + 3) * 169 + (h1 - h2 + 6) * 13 + (w1 - w2 + 6);
        v = bt[bi * 16 + h] * LOG2E;
    }
    out[idx] = v;
}

// ---------------- KV projection GEMM ----------------
// A: x_bf16 [50176][512], B: kv_w_bf16 [1024][512] (B^T form: D = A.B^T)
// tile 128x128, BK=64, 4 waves (2x2), each 64x64. LDS stride 72 => conflict-free.
__global__ __launch_bounds__(256) void gemm_kv(const ushort_t* __restrict__ A,
                                               const ushort_t* __restrict__ Bw,
                                               const float* __restrict__ kvb,
                                               ushort_t* __restrict__ Ko,
                                               ushort_t* __restrict__ Vo) {
    __shared__ ushort_t As[128 * 72];
    __shared__ ushort_t Bs[128 * 72];
    const int tid = threadIdx.x;
    const int lane = tid & 63, wave = tid >> 6;
    const int lrow = lane & 15, quad = lane >> 4;
    const int wr = wave >> 1, wc = wave & 1;
    const long arow0 = (long)blockIdx.x * 128;
    const int brow0 = blockIdx.y * 128;

    f32x4 acc[4][4];
#pragma unroll
    for (int i = 0; i < 4; ++i)
#pragma unroll
        for (int j = 0; j < 4; ++j) acc[i][j] = (f32x4){0.f, 0.f, 0.f, 0.f};

    for (int k0 = 0; k0 < 512; k0 += 64) {
        short8 ar[4], br[4];
#pragma unroll
        for (int it = 0; it < 4; ++it) {
            int c = it * 256 + tid;
            int row = c >> 3, cc = c & 7;
            ar[it] = *(const short8*)&A[(arow0 + row) * 512 + k0 + cc * 8];
            br[it] = *(const short8*)&Bw[(long)(brow0 + row) * 512 + k0 + cc * 8];
        }
        __syncthreads();
#pragma unroll
        for (int it = 0; it < 4; ++it) {
            int c = it * 256 + tid;
            int row = c >> 3, cc = c & 7;
            *(short8*)&As[row * 72 + cc * 8] = ar[it];
            *(short8*)&Bs[row * 72 + cc * 8] = br[it];
        }
        __syncthreads();
#pragma unroll
        for (int kk = 0; kk < 64; kk += 32) {
            short8 af[4], bf[4];
#pragma unroll
            for (int i = 0; i < 4; ++i)
                af[i] = *(const short8*)&As[(wr * 64 + i * 16 + lrow) * 72 + kk + quad * 8];
#pragma unroll
            for (int j = 0; j < 4; ++j)
                bf[j] = *(const short8*)&Bs[(wc * 64 + j * 16 + lrow) * 72 + kk + quad * 8];
#pragma unroll
            for (int i = 0; i < 4; ++i)
#pragma unroll
                for (int j = 0; j < 4; ++j)
                    acc[i][j] = mfma16(af[i], bf[j], acc[i][j]);
        }
    }
    // epilogue: scatter to K/V [b_,h,n,d] bf16, + kv_b
#pragma unroll
    for (int i = 0; i < 4; ++i) {
        int mb = (int)arow0 + wr * 64 + i * 16 + quad * 4;
#pragma unroll
        for (int r = 0; r < 4; ++r) {
            int m = mb + r;
            int b_ = m / 196;
            int n = m - b_ * 196;
#pragma unroll
            for (int j = 0; j < 4; ++j) {
                int cI = brow0 + wc * 64 + j * 16 + lrow;
                float v = acc[i][j][r] + kvb[cI];
                int hh = (cI >> 5) & 15, d = cI & 31;
                ushort_t* dst = (cI >> 9) ? Vo : Ko;
                dst[((((long)b_ << 4) + hh) * 196 + n) * 32 + d] = f2bf(v);
            }
        }
    }
}

// ---------------- fused attention (swapped-QK layout) ----------------
// one block per (b_, h); 8 waves (512 thr), row-tiles rt = wave, wave+8.
// QK^T computed as mfma(K, Q): lane(lrow,quad) reg r holds
//   S[q = rt*16 + lrow][k = ct*16 + quad*4 + r]
// -> softmax reduction is lane-local + 2 shuffles, bias loads are float4,
//    P writes are conflict-free ds_write_b64 of cvt_pk pairs.
// K read directly from global (no Ks LDS): rows 196..207 read past the head
// (next head / vbuf start, finite bf16) and are masked by bias = -1e30.
// P stored unnormalized; 1/sum folded into the epilogue.
__global__ __launch_bounds__(512, 4) void attn_k(const ushort_t* __restrict__ Kb,
                                                 const ushort_t* __restrict__ Vb,
                                                 const ushort_t* __restrict__ Qb,
                                                 const float* __restrict__ biasF,
                                                 ushort_t* __restrict__ Ob) {
    const int tid = threadIdx.x, lane = tid & 63, wave = tid >> 6;
    const int lrow = lane & 15, quad = lane >> 4;
    const int bh = blockIdx.x;           // = b_*16 + h
    const int b_ = bh >> 4, h = bh & 15;
    const int Bq = b_ >> 6;              // B_dim = 64

    __shared__ ushort_t Vt[32 * 232];    // [d][j], stride 232 (conflict-free b128)
    __shared__ ushort_t Ps[8][16 * 232]; // per-wave P scratch [q][k]

    const long kvoff = (long)bh * 6272;  // 196*32

    for (int i = tid; i < 6272; i += 512) {          // V -> LDS transposed
        int n = i >> 5, d = i & 31;
        Vt[d * 232 + n] = Vb[kvoff + i];
    }
    for (int i = tid; i < 32 * 36; i += 512) {       // V^T pad cols 196..231
        int d = i / 36, j = i - d * 36;
        Vt[d * 232 + 196 + j] = 0;
    }
    for (int i = lane; i < 256; i += 64) {           // P pad cols 208..223 (per wave)
        int r = i >> 4, cp = i & 15;
        Ps[wave][r * 232 + 208 + cp] = 0;
    }
    __syncthreads();

    const float* biasH = biasF + h * 43264;
    const long qbase = (((long)Bq * 16 + h) * 196) * 32;
    const ushort_t* Kh = Kb + kvoff;

    for (int rt = wave; rt < 13; rt += 8) {
        const int qrow = rt * 16 + lrow;             // logical q row (0..207)
        const int qr = qrow > 195 ? 195 : qrow;      // clamp for the Q load only
        short8 qf = *(const short8*)&Qb[qbase + (long)qr * 32 + quad * 8];

        f32x4 s[13];
#pragma unroll
        for (int ct = 0; ct < 13; ++ct) {
            short8 kf = *(const short8*)&Kh[(ct * 16 + lrow) * 32 + quad * 8];
            s[ct] = mfma16(kf, qf, (f32x4){0.f, 0.f, 0.f, 0.f});
        }

        // bias add (float4: k is r-contiguous) + row max
        float mx = -3e38f;
        const float* bp = biasH + (long)qrow * 208 + quad * 4;
#pragma unroll
        for (int ct = 0; ct < 13; ++ct) {
            float4 bv = *(const float4*)&bp[ct * 16];
            s[ct][0] += bv.x; s[ct][1] += bv.y; s[ct][2] += bv.z; s[ct][3] += bv.w;
            mx = fmaxf(mx, fmaxf(fmaxf(s[ct][0], s[ct][1]), fmaxf(s[ct][2], s[ct][3])));
        }
        mx = fmaxf(mx, __shfl_xor(mx, 16));
        mx = fmaxf(mx, __shfl_xor(mx, 32));

        float sm = 0.f;
#pragma unroll
        for (int ct = 0; ct < 13; ++ct)
#pragma unroll
            for (int r = 0; r < 4; ++r) {
                float p = exp2f(s[ct][r] - mx);      // native v_exp_f32 (log2 domain)
                s[ct][r] = p;
                sm += p;
            }
        sm += __shfl_xor(sm, 16);
        sm += __shfl_xor(sm, 32);
        const float sminv = 1.0f / sm;

        // pack P (unnormalized) -> LDS: 13 conflict-free b64 writes
        ushort_t* prow = &Ps[wave][lrow * 232];
#pragma unroll
        for (int ct = 0; ct < 13; ++ct) {
            uint32_t w0, w1;
            asm("v_cvt_pk_bf16_f32 %0, %1, %2" : "=v"(w0) : "v"(s[ct][0]), "v"(s[ct][1]));
            asm("v_cvt_pk_bf16_f32 %0, %1, %2" : "=v"(w1) : "v"(s[ct][2]), "v"(s[ct][3]));
            uint2 w; w.x = w0; w.y = w1;
            *(uint2*)&prow[ct * 16 + quad * 4] = w;
        }
        asm volatile("s_waitcnt lgkmcnt(0)" ::: "memory");  // in-wave LDS RAW fence

        f32x4 o0 = (f32x4){0.f,0.f,0.f,0.f}, o1 = (f32x4){0.f,0.f,0.f,0.f};
#pragma unroll
        for (int ks = 0; ks < 7; ++ks) {
            short8 pf = *(const short8*)&prow[ks * 32 + quad * 8];
            short8 v0 = *(const short8*)&Vt[lrow * 232 + ks * 32 + quad * 8];
            short8 v1 = *(const short8*)&Vt[(16 + lrow) * 232 + ks * 32 + quad * 8];
            o0 = mfma16(pf, v0, o0);
            o1 = mfma16(pf, v1, o1);
        }
        const long obase = (long)b_ * 196 * 512 + h * 32;
#pragma unroll
        for (int r = 0; r < 4; ++r) {
            float sv = __shfl(sminv, quad * 4 + r);  // sum for output row quad*4+r
            int m = rt * 16 + quad * 4 + r;
            if (m < 196) {
                Ob[obase + (long)m * 512 + lrow]      = f2bf(o0[r] * sv);
                Ob[obase + (long)m * 512 + 16 + lrow] = f2bf(o1[r] * sv);
            }
        }
    }
}

// ---------------- output projection GEMM ----------------
__global__ __launch_bounds__(256) void gemm_proj(const ushort_t* __restrict__ A,
                                                 const ushort_t* __restrict__ Bw,
                                                 const float* __restrict__ pb,
                                                 float* __restrict__ out) {
    __shared__ ushort_t As[128 * 72];
    __shared__ ushort_t Bs[128 * 72];
    const int tid = threadIdx.x;
    const int lane = tid & 63, wave = tid >> 6;
    const int lrow = lane & 15, quad = lane >> 4;
    const int wr = wave >> 1, wc = wave & 1;
    const long arow0 = (long)blockIdx.x * 128;
    const int brow0 = blockIdx.y * 128;

    f32x4 acc[4][4];
#pragma unroll
    for (int i = 0; i < 4; ++i)
#pragma unroll
        for (int j = 0; j < 4; ++j) acc[i][j] = (f32x4){0.f, 0.f, 0.f, 0.f};

    for (int k0 = 0; k0 < 512; k0 += 64) {
        short8 ar[4], br[4];
#pragma unroll
        for (int it = 0; it < 4; ++it) {
            int c = it * 256 + tid;
            int row = c >> 3, cc = c & 7;
            ar[it] = *(const short8*)&A[(arow0 + row) * 512 + k0 + cc * 8];
            br[it] = *(const short8*)&Bw[(long)(brow0 + row) * 512 + k0 + cc * 8];
        }
        __syncthreads();
#pragma unroll
        for (int it = 0; it < 4; ++it) {
            int c = it * 256 + tid;
            int row = c >> 3, cc = c & 7;
            *(short8*)&As[row * 72 + cc * 8] = ar[it];
            *(short8*)&Bs[row * 72 + cc * 8] = br[it];
        }
        __syncthreads();
#pragma unroll
        for (int kk = 0; kk < 64; kk += 32) {
            short8 af[4], bf[4];
#pragma unroll
            for (int i = 0; i < 4; ++i)
                af[i] = *(const short8*)&As[(wr * 64 + i * 16 + lrow) * 72 + kk + quad * 8];
#pragma unroll
            for (int j = 0; j < 4; ++j)
                bf[j] = *(const short8*)&Bs[(wc * 64 + j * 16 + lrow) * 72 + kk + quad * 8];
#pragma unroll
            for (int i = 0; i < 4; ++i)
#pragma unroll
                for (int j = 0; j < 4; ++j)
                    acc[i][j] = mfma16(af[i], bf[j], acc[i][j]);
        }
    }
#pragma unroll
    for (int i = 0; i < 4; ++i) {
        long mb = arow0 + wr * 64 + i * 16 + quad * 4;
#pragma unroll
        for (int r = 0; r < 4; ++r) {
            long m = mb + r;
#pragma unroll
            for (int j = 0; j < 4; ++j) {
                int cI = brow0 + wc * 64 + j * 16 + lrow;
                out[m * 512 + cI] = acc[i][j][r] + pb[cI];
            }
        }
    }
}

// ---------------- launch ----------------

extern "C" void kernel_launch(void* const* d_in, const int* in_sizes, int n_in,
                              void* d_out, int out_size, void* d_ws, size_t ws_size,
                              hipStream_t stream) {
    const float* x   = (const float*)d_in[0];
    const float* qg  = (const float*)d_in[1];
    const float* kvw = (const float*)d_in[2];
    const float* kvb = (const float*)d_in[3];
    const float* pw  = (const float*)d_in[4];
    const float* pb  = (const float*)d_in[5];
    const float* bt  = (const float*)d_in[6];
    float* out = (float*)d_out;

    char* ws = (char*)d_ws;
    ushort_t* xb    = (ushort_t*)(ws);                 // 51,380,224 B  (also aliased as attn out)
    ushort_t* kbuf  = (ushort_t*)(ws + 51380224);      // 51,380,224 B
    ushort_t* vbuf  = (ushort_t*)(ws + 102760448);     // 51,380,224 B (also K overread pad)
    ushort_t* kvwb  = (ushort_t*)(ws + 154140672);     //  1,048,576 B
    ushort_t* pwb   = (ushort_t*)(ws + 155189248);     //    524,288 B
    ushort_t* qb    = (ushort_t*)(ws + 155713536);     //    802,816 B
    float*    biasF = (float*)   (ws + 156516352);     //  2,768,896 B -> total 159,285,248 B
    ushort_t* obuf  = xb;  // x dead after gemm_kv; reuse for attention output

    cvt_x_k<<<25088, 256, 0, stream>>>((const float4*)x, (u16x4*)xb, 6422528);
    cvt_small_k<<<1160, 256, 0, stream>>>((const float4*)kvw, (const float4*)pw,
                                          (const float4*)qg,
                                          (u16x4*)kvwb, (u16x4*)pwb, (u16x4*)qb);
    bias_k<<<2704, 256, 0, stream>>>(bt, biasF);
    gemm_kv<<<dim3(392, 8), 256, 0, stream>>>(xb, kvwb, kvb, kbuf, vbuf);
    attn_k<<<4096, 512, 0, stream>>>(kbuf, vbuf, qb, biasF, obuf);
    gemm_proj<<<dim3(392, 4), 256, 0, stream>>>(obuf, pwb, pb, out);
}

// Round 3
// 442.448 us; speedup vs baseline: 1.1155x; 1.1155x over previous
//
#include <hip/hip_runtime.h>
#include <stdint.h>

typedef __attribute__((ext_vector_type(8))) short short8;      // 8 x bf16 (4 VGPRs) MFMA A/B frag
typedef __attribute__((ext_vector_type(4))) float f32x4;       // MFMA C/D frag
typedef __attribute__((ext_vector_type(4))) unsigned short u16x4;

typedef unsigned short ushort_t;

__device__ __forceinline__ unsigned short f2bf(float f) {
    union { float f; uint32_t u; } c; c.f = f;
    uint32_t u = c.u;
    return (unsigned short)((u + 0x7FFFu + ((u >> 16) & 1u)) >> 16);   // RNE
}

__device__ __forceinline__ f32x4 mfma16(short8 a, short8 b, f32x4 c) {
    return __builtin_amdgcn_mfma_f32_16x16x32_bf16(a, b, c, 0, 0, 0);
}

#define LOG2E 1.4426950408889634f

// ---------------- converters ----------------

__global__ __launch_bounds__(256) void cvt_x_k(const float4* __restrict__ in,
                                               u16x4* __restrict__ out, int n4) {
    int i = blockIdx.x * 256 + threadIdx.x;
    if (i < n4) {
        float4 v = in[i];
        u16x4 o;
        o[0] = f2bf(v.x); o[1] = f2bf(v.y); o[2] = f2bf(v.z); o[3] = f2bf(v.w);
        out[i] = o;
    }
}

// kv_w (131072 groups) + proj_w (65536) + q_global*scale*log2e (100352) = 296960 groups
__global__ __launch_bounds__(256) void cvt_small_k(const float4* __restrict__ kvw,
                                                   const float4* __restrict__ pw,
                                                   const float4* __restrict__ qg,
                                                   u16x4* __restrict__ kvwb,
                                                   u16x4* __restrict__ pwb,
                                                   u16x4* __restrict__ qb) {
    // 32^-0.5 * log2(e): softmax computed in exp2 domain
    const float qs = 0.17677669529663687f * LOG2E;
    int i = blockIdx.x * 256 + threadIdx.x;
    if (i < 131072) {
        float4 v = kvw[i];
        u16x4 o; o[0]=f2bf(v.x); o[1]=f2bf(v.y); o[2]=f2bf(v.z); o[3]=f2bf(v.w);
        kvwb[i] = o;
    } else if (i < 196608) {
        int j = i - 131072;
        float4 v = pw[j];
        u16x4 o; o[0]=f2bf(v.x); o[1]=f2bf(v.y); o[2]=f2bf(v.z); o[3]=f2bf(v.w);
        pwb[j] = o;
    } else {
        int j = i - 196608;   // < 100352
        float4 v = qg[j];
        u16x4 o; o[0]=f2bf(v.x*qs); o[1]=f2bf(v.y*qs); o[2]=f2bf(v.z*qs); o[3]=f2bf(v.w*qs);
        qb[j] = o;
    }
}

// bias_full[h][i][j], i,j in [0,208); -1e30 on pad so softmax masks pad keys.
// Values pre-scaled by log2(e) (softmax runs in exp2 domain).
__global__ __launch_bounds__(256) void bias_k(const float* __restrict__ bt,
                                              float* __restrict__ out) {
    int idx = blockIdx.x * 256 + threadIdx.x;        // 16*208*208 = 692224 exact
    int h = idx / 43264;
    int rem = idx - h * 43264;
    int i = rem / 208;
    int j = rem - i * 208;
    float v = -1e30f;
    if (i < 196 && j < 196) {
        int t1 = i / 49, r1 = i - t1 * 49, h1 = r1 / 7, w1 = r1 - h1 * 7;
        int t2 = j / 49, r2 = j - t2 * 49, h2 = r2 / 7, w2 = r2 - h2 * 7;
        int bi = (t1 - t2 + 3) * 169 + (h1 - h2 + 6) * 13 + (w1 - w2 + 6);
        v = bt[bi * 16 + h] * LOG2E;
    }
    out[idx] = v;
}

// ---------------- KV projection GEMM ----------------
// A: x_bf16 [50176][512], B: kv_w_bf16 [1024][512] (B^T form: D = A.B^T)
// tile 128x128, BK=64, 4 waves (2x2), each 64x64. LDS stride 72 => conflict-free.
__global__ __launch_bounds__(256) void gemm_kv(const ushort_t* __restrict__ A,
                                               const ushort_t* __restrict__ Bw,
                                               const float* __restrict__ kvb,
                                               ushort_t* __restrict__ Ko,
                                               ushort_t* __restrict__ Vo) {
    __shared__ ushort_t As[128 * 72];
    __shared__ ushort_t Bs[128 * 72];
    const int tid = threadIdx.x;
    const int lane = tid & 63, wave = tid >> 6;
    const int lrow = lane & 15, quad = lane >> 4;
    const int wr = wave >> 1, wc = wave & 1;
    const long arow0 = (long)blockIdx.x * 128;
    const int brow0 = blockIdx.y * 128;

    f32x4 acc[4][4];
#pragma unroll
    for (int i = 0; i < 4; ++i)
#pragma unroll
        for (int j = 0; j < 4; ++j) acc[i][j] = (f32x4){0.f, 0.f, 0.f, 0.f};

    for (int k0 = 0; k0 < 512; k0 += 64) {
        short8 ar[4], br[4];
#pragma unroll
        for (int it = 0; it < 4; ++it) {
            int c = it * 256 + tid;
            int row = c >> 3, cc = c & 7;
            ar[it] = *(const short8*)&A[(arow0 + row) * 512 + k0 + cc * 8];
            br[it] = *(const short8*)&Bw[(long)(brow0 + row) * 512 + k0 + cc * 8];
        }
        __syncthreads();
#pragma unroll
        for (int it = 0; it < 4; ++it) {
            int c = it * 256 + tid;
            int row = c >> 3, cc = c & 7;
            *(short8*)&As[row * 72 + cc * 8] = ar[it];
            *(short8*)&Bs[row * 72 + cc * 8] = br[it];
        }
        __syncthreads();
#pragma unroll
        for (int kk = 0; kk < 64; kk += 32) {
            short8 af[4], bf[4];
#pragma unroll
            for (int i = 0; i < 4; ++i)
                af[i] = *(const short8*)&As[(wr * 64 + i * 16 + lrow) * 72 + kk + quad * 8];
#pragma unroll
            for (int j = 0; j < 4; ++j)
                bf[j] = *(const short8*)&Bs[(wc * 64 + j * 16 + lrow) * 72 + kk + quad * 8];
#pragma unroll
            for (int i = 0; i < 4; ++i)
#pragma unroll
                for (int j = 0; j < 4; ++j)
                    acc[i][j] = mfma16(af[i], bf[j], acc[i][j]);
        }
    }
    // epilogue: scatter to K/V [b_,h,n,d] bf16, + kv_b
#pragma unroll
    for (int i = 0; i < 4; ++i) {
        int mb = (int)arow0 + wr * 64 + i * 16 + quad * 4;
#pragma unroll
        for (int r = 0; r < 4; ++r) {
            int m = mb + r;
            int b_ = m / 196;
            int n = m - b_ * 196;
#pragma unroll
            for (int j = 0; j < 4; ++j) {
                int cI = brow0 + wc * 64 + j * 16 + lrow;
                float v = acc[i][j][r] + kvb[cI];
                int hh = (cI >> 5) & 15, d = cI & 31;
                ushort_t* dst = (cI >> 9) ? Vo : Ko;
                dst[((((long)b_ << 4) + hh) * 196 + n) * 32 + d] = f2bf(v);
            }
        }
    }
}

// ---------------- fused attention (swapped-QK layout, 4 waves, no spill) ----------------
// one block per (b_, h); 4 waves (256 thr), row-tiles rt = wave, wave+4, ...
// QK^T computed as mfma(K, Q): lane(lrow,quad) reg r holds
//   S[q = rt*16 + lrow][k = ct*16 + quad*4 + r]
// -> softmax reduction is lane-local + 2 shuffles, bias loads are float4,
//    P writes are ds_write_b64 of cvt_pk pairs.
// K read directly from global (no Ks LDS): rows 196..207 read past the head
// (next head / vbuf start, finite bf16) and are masked by bias = -1e30.
// Vt n-index XOR-swizzled (n ^ ((d>>3)&3)<<3) so the transpose-staging scalar
// writes (lanes sweep d) hit 4 distinct banks per former {d,d+8,d+16,d+24}
// conflict group; reads use the same XOR (bits>=3 only: b128 alignment kept).
// P stored unnormalized; 1/sum folded into the epilogue.
__global__ __launch_bounds__(256) void attn_k(const ushort_t* __restrict__ Kb,
                                              const ushort_t* __restrict__ Vb,
                                              const ushort_t* __restrict__ Qb,
                                              const float* __restrict__ biasF,
                                              ushort_t* __restrict__ Ob) {
    const int tid = threadIdx.x, lane = tid & 63, wave = tid >> 6;
    const int lrow = lane & 15, quad = lane >> 4;
    const int bh = blockIdx.x;           // = b_*16 + h
    const int b_ = bh >> 4, h = bh & 15;
    const int Bq = b_ >> 6;              // B_dim = 64

    __shared__ ushort_t Vt[32 * 232];    // [d][n'], n' = n ^ (((d>>3)&3)<<3)
    __shared__ ushort_t Ps[4][16 * 232]; // per-wave P scratch [q][k]

    const long kvoff = (long)bh * 6272;  // 196*32

    // pre-zero the pad closure n in [192,224) (swizzle is a bijection within
    // each 32-block; staging below overwrites the real n<196 slots)
    for (int i = tid; i < 1024; i += 256) {
        int d = i >> 5, n = 192 + (i & 31);
        Vt[d * 232 + n] = 0;
    }
    __syncthreads();
    for (int i = tid; i < 6272; i += 256) {          // V -> LDS transposed, swizzled
        int n = i >> 5, d = i & 31;
        int g = (d >> 3) & 3;
        Vt[d * 232 + (n ^ (g << 3))] = Vb[kvoff + i];
    }
    for (int i = lane; i < 256; i += 64) {           // P pad cols 208..223 (per wave)
        int r = i >> 4, cp = i & 15;
        Ps[wave][r * 232 + 208 + cp] = 0;
    }
    __syncthreads();

    const float* biasH = biasF + h * 43264;
    const long qbase = (((long)Bq * 16 + h) * 196) * 32;
    const ushort_t* Kh = Kb + kvoff;
    const int vsw0 = ((lrow >> 3) & 1) << 3;         // swizzle for d = lrow
    const int vsw1 = (2 | ((lrow >> 3) & 1)) << 3;   // swizzle for d = 16 + lrow

    for (int rt = wave; rt < 13; rt += 4) {
        const int qrow = rt * 16 + lrow;             // logical q row (0..207)
        const int qr = qrow > 195 ? 195 : qrow;      // clamp for the Q load only
        short8 qf = *(const short8*)&Qb[qbase + (long)qr * 32 + quad * 8];

        f32x4 s[13];
#pragma unroll
        for (int ct = 0; ct < 13; ++ct) {
            short8 kf = *(const short8*)&Kh[(ct * 16 + lrow) * 32 + quad * 8];
            s[ct] = mfma16(kf, qf, (f32x4){0.f, 0.f, 0.f, 0.f});
        }

        // bias add (float4: k is r-contiguous) + row max
        float mx = -3e38f;
        const float* bp = biasH + (long)qrow * 208 + quad * 4;
#pragma unroll
        for (int ct = 0; ct < 13; ++ct) {
            float4 bv = *(const float4*)&bp[ct * 16];
            s[ct][0] += bv.x; s[ct][1] += bv.y; s[ct][2] += bv.z; s[ct][3] += bv.w;
            mx = fmaxf(mx, fmaxf(fmaxf(s[ct][0], s[ct][1]), fmaxf(s[ct][2], s[ct][3])));
        }
        mx = fmaxf(mx, __shfl_xor(mx, 16));
        mx = fmaxf(mx, __shfl_xor(mx, 32));

        float sm = 0.f;
#pragma unroll
        for (int ct = 0; ct < 13; ++ct)
#pragma unroll
            for (int r = 0; r < 4; ++r) {
                float p = exp2f(s[ct][r] - mx);      // native v_exp_f32 (log2 domain)
                s[ct][r] = p;
                sm += p;
            }
        sm += __shfl_xor(sm, 16);
        sm += __shfl_xor(sm, 32);
        const float sminv = 1.0f / sm;

        // pack P (unnormalized) -> LDS: 13 b64 writes
        ushort_t* prow = &Ps[wave][lrow * 232];
#pragma unroll
        for (int ct = 0; ct < 13; ++ct) {
            uint32_t w0, w1;
            asm("v_cvt_pk_bf16_f32 %0, %1, %2" : "=v"(w0) : "v"(s[ct][0]), "v"(s[ct][1]));
            asm("v_cvt_pk_bf16_f32 %0, %1, %2" : "=v"(w1) : "v"(s[ct][2]), "v"(s[ct][3]));
            uint2 w; w.x = w0; w.y = w1;
            *(uint2*)&prow[ct * 16 + quad * 4] = w;
        }
        asm volatile("s_waitcnt lgkmcnt(0)" ::: "memory");  // in-wave LDS RAW fence

        f32x4 o0 = (f32x4){0.f,0.f,0.f,0.f}, o1 = (f32x4){0.f,0.f,0.f,0.f};
#pragma unroll
        for (int ks = 0; ks < 7; ++ks) {
            short8 pf = *(const short8*)&prow[ks * 32 + quad * 8];
            short8 v0 = *(const short8*)&Vt[lrow * 232 + ((ks * 32 + quad * 8) ^ vsw0)];
            short8 v1 = *(const short8*)&Vt[(16 + lrow) * 232 + ((ks * 32 + quad * 8) ^ vsw1)];
            o0 = mfma16(pf, v0, o0);
            o1 = mfma16(pf, v1, o1);
        }
        const long obase = (long)b_ * 196 * 512 + h * 32;
#pragma unroll
        for (int r = 0; r < 4; ++r) {
            float sv = __shfl(sminv, quad * 4 + r);  // sum for output row quad*4+r
            int m = rt * 16 + quad * 4 + r;
            if (m < 196) {
                Ob[obase + (long)m * 512 + lrow]      = f2bf(o0[r] * sv);
                Ob[obase + (long)m * 512 + 16 + lrow] = f2bf(o1[r] * sv);
            }
        }
    }
}

// ---------------- output projection GEMM ----------------
__global__ __launch_bounds__(256) void gemm_proj(const ushort_t* __restrict__ A,
                                                 const ushort_t* __restrict__ Bw,
                                                 const float* __restrict__ pb,
                                                 float* __restrict__ out) {
    __shared__ ushort_t As[128 * 72];
    __shared__ ushort_t Bs[128 * 72];
    const int tid = threadIdx.x;
    const int lane = tid & 63, wave = tid >> 6;
    const int lrow = lane & 15, quad = lane >> 4;
    const int wr = wave >> 1, wc = wave & 1;
    const long arow0 = (long)blockIdx.x * 128;
    const int brow0 = blockIdx.y * 128;

    f32x4 acc[4][4];
#pragma unroll
    for (int i = 0; i < 4; ++i)
#pragma unroll
        for (int j = 0; j < 4; ++j) acc[i][j] = (f32x4){0.f, 0.f, 0.f, 0.f};

    for (int k0 = 0; k0 < 512; k0 += 64) {
        short8 ar[4], br[4];
#pragma unroll
        for (int it = 0; it < 4; ++it) {
            int c = it * 256 + tid;
            int row = c >> 3, cc = c & 7;
            ar[it] = *(const short8*)&A[(arow0 + row) * 512 + k0 + cc * 8];
            br[it] = *(const short8*)&Bw[(long)(brow0 + row) * 512 + k0 + cc * 8];
        }
        __syncthreads();
#pragma unroll
        for (int it = 0; it < 4; ++it) {
            int c = it * 256 + tid;
            int row = c >> 3, cc = c & 7;
            *(short8*)&As[row * 72 + cc * 8] = ar[it];
            *(short8*)&Bs[row * 72 + cc * 8] = br[it];
        }
        __syncthreads();
#pragma unroll
        for (int kk = 0; kk < 64; kk += 32) {
            short8 af[4], bf[4];
#pragma unroll
            for (int i = 0; i < 4; ++i)
                af[i] = *(const short8*)&As[(wr * 64 + i * 16 + lrow) * 72 + kk + quad * 8];
#pragma unroll
            for (int j = 0; j < 4; ++j)
                bf[j] = *(const short8*)&Bs[(wc * 64 + j * 16 + lrow) * 72 + kk + quad * 8];
#pragma unroll
            for (int i = 0; i < 4; ++i)
#pragma unroll
                for (int j = 0; j < 4; ++j)
                    acc[i][j] = mfma16(af[i], bf[j], acc[i][j]);
        }
    }
#pragma unroll
    for (int i = 0; i < 4; ++i) {
        long mb = arow0 + wr * 64 + i * 16 + quad * 4;
#pragma unroll
        for (int r = 0; r < 4; ++r) {
            long m = mb + r;
#pragma unroll
            for (int j = 0; j < 4; ++j) {
                int cI = brow0 + wc * 64 + j * 16 + lrow;
                out[m * 512 + cI] = acc[i][j][r] + pb[cI];
            }
        }
    }
}

// ---------------- launch ----------------

extern "C" void kernel_launch(void* const* d_in, const int* in_sizes, int n_in,
                              void* d_out, int out_size, void* d_ws, size_t ws_size,
                              hipStream_t stream) {
    const float* x   = (const float*)d_in[0];
    const float* qg  = (const float*)d_in[1];
    const float* kvw = (const float*)d_in[2];
    const float* kvb = (const float*)d_in[3];
    const float* pw  = (const float*)d_in[4];
    const float* pb  = (const float*)d_in[5];
    const float* bt  = (const float*)d_in[6];
    float* out = (float*)d_out;

    char* ws = (char*)d_ws;
    ushort_t* xb    = (ushort_t*)(ws);                 // 51,380,224 B  (also aliased as attn out)
    ushort_t* kbuf  = (ushort_t*)(ws + 51380224);      // 51,380,224 B
    ushort_t* vbuf  = (ushort_t*)(ws + 102760448);     // 51,380,224 B (also K overread pad)
    ushort_t* kvwb  = (ushort_t*)(ws + 154140672);     //  1,048,576 B
    ushort_t* pwb   = (ushort_t*)(ws + 155189248);     //    524,288 B
    ushort_t* qb    = (ushort_t*)(ws + 155713536);     //    802,816 B
    float*    biasF = (float*)   (ws + 156516352);     //  2,768,896 B -> total 159,285,248 B
    ushort_t* obuf  = xb;  // x dead after gemm_kv; reuse for attention output

    cvt_x_k<<<25088, 256, 0, stream>>>((const float4*)x, (u16x4*)xb, 6422528);
    cvt_small_k<<<1160, 256, 0, stream>>>((const float4*)kvw, (const float4*)pw,
                                          (const float4*)qg,
                                          (u16x4*)kvwb, (u16x4*)pwb, (u16x4*)qb);
    bias_k<<<2704, 256, 0, stream>>>(bt, biasF);
    gemm_kv<<<dim3(392, 8), 256, 0, stream>>>(xb, kvwb, kvb, kbuf, vbuf);
    attn_k<<<4096, 256, 0, stream>>>(kbuf, vbuf, qb, biasF, obuf);
    gemm_proj<<<dim3(392, 4), 256, 0, stream>>>(obuf, pwb, pb, out);
}